// Round 1
// baseline (176.726 us; speedup 1.0000x reference)
//
#include <hip/hip_runtime.h>

// Problem constants (fixed by the reference):
//   x:      (4, 3, 1024, 2048) fp32
//   weight: (3, 3, 3, 3)       fp32   w[o][c][p][q]
//   bn:     (1024, 2048)       int32
//   out:    (4, 3, 1024, 2048) fp32; active region [:, :, :1022, :1022]
//
// Structure exploited:
//   - gather column index is q in {0,1,2}: only x[:, :, :, 0:3] is ever read
//   - j1 = j % 256  ->  pre-mask activation is periodic in j with period 256
//   => compute v[o][jm] once per (b, i) row, then stream-write the 2048-wide
//      row applying the per-j mask. Kernel is HBM-write-bound (~100 MB out).

#define HH 1024
#define WW 2048
#define HI 1022
#define WJ 1022

__global__ __launch_bounds__(256, 4) void dis_conv_kernel(
    const float* __restrict__ x,
    const float* __restrict__ w,
    const int*   __restrict__ bn,
    float*       __restrict__ out)
{
    const int bi = blockIdx.x;      // 0..4095
    const int b  = bi >> 10;        // batch 0..3
    const int i  = bi & 1023;       // output row 0..1023
    const int t  = threadIdx.x;     // 0..255

    __shared__ __align__(16) float v[3][256];     // v[o][jm], jm = j % 256
    __shared__ __align__(16) float mask_s[1024];  // mask per j, 0 for j>=1022

    const bool activeRow = (i < HI);

    // ---- Phase 1: compute v[o][jm] for this row (jm = t) ----
    float acc0 = 0.f, acc1 = 0.f, acc2 = 0.f;
    if (activeRow) {
        const int jm = t;
        #pragma unroll
        for (int p = 0; p < 3; ++p) {
            const int r = i + p;                       // <= 1023
            const int* bnrow = bn + (size_t)r * WW;
            #pragma unroll
            for (int q = 0; q < 3; ++q) {
                int Rv = r + bnrow[jm + q];            // jm+q <= 257
                if (Rv < 0) Rv += HH;                  // numpy negative-index wrap
                const float* xp = x + ((size_t)b * 3) * HH * WW + (size_t)Rv * WW + q;
                #pragma unroll
                for (int c = 0; c < 3; ++c) {
                    const float xv = xp[(size_t)c * HH * WW];
                    acc0 += xv * w[ 0 + c * 9 + p * 3 + q];
                    acc1 += xv * w[27 + c * 9 + p * 3 + q];
                    acc2 += xv * w[54 + c * 9 + p * 3 + q];
                }
            }
        }
    }
    v[0][t] = acc0;
    v[1][t] = acc1;
    v[2][t] = acc2;

    // ---- Phase 1.5: mask row into LDS (zero-padded to 1024) ----
    #pragma unroll
    for (int jj = 0; jj < 4; ++jj) {
        const int j = t + jj * 256;
        float m = 0.f;
        if (activeRow && j < WJ) {
            // mask = (i+2) + bn[i+2, j+2] < H
            m = ((i + 2) + bn[(size_t)(i + 2) * WW + (j + 2)] < HH) ? 1.f : 0.f;
        }
        mask_s[j] = m;
    }
    __syncthreads();

    // ---- Phase 2: stream the 3 output rows (float4 stores) ----
    #pragma unroll
    for (int o = 0; o < 3; ++o) {
        float* orow = out + (((size_t)b * 3 + o) * HH + i) * WW;
        #pragma unroll
        for (int it = 0; it < 2; ++it) {
            const int j4 = (t + it * 256) * 4;   // 0..2044 step 4, wave-uniform branch
            float4 val;
            if (j4 < 1024) {
                const float4 vv = *(const float4*)&v[o][j4 & 255];
                const float4 mm = *(const float4*)&mask_s[j4];
                val = make_float4(vv.x * mm.x, vv.y * mm.y, vv.z * mm.z, vv.w * mm.w);
            } else {
                val = make_float4(0.f, 0.f, 0.f, 0.f);
            }
            *(float4*)&orow[j4] = val;
        }
    }
}

extern "C" void kernel_launch(void* const* d_in, const int* in_sizes, int n_in,
                              void* d_out, int out_size, void* d_ws, size_t ws_size,
                              hipStream_t stream) {
    const float* x   = (const float*)d_in[0];
    const float* w   = (const float*)d_in[1];
    const int*   bn  = (const int*)d_in[2];
    float*       out = (float*)d_out;

    // one block per (b, i) row: 4 * 1024 = 4096 blocks
    dis_conv_kernel<<<dim3(4096), dim3(256), 0, stream>>>(x, w, bn, out);
}